// Round 1
// baseline (11.276 us; speedup 1.0000x reference)
//
#include <hip/hip_runtime.h>

#define FEAT_DIM 2048
#define BATCH 1024
#define CLAMP_MIN 1e-12f
#define CLAMP_MAX 1e12f

// Kernel 1: one block per batch row. Compute dist[b] = sum((x[b]-centers[labels[b]])^2)/FEAT_DIM
__global__ void __launch_bounds__(256) center_dist_kernel(
    const float* __restrict__ x,
    const int* __restrict__ labels,
    const float* __restrict__ centers,
    float* __restrict__ row_dist) {
    const int b = blockIdx.x;
    const int t = threadIdx.x;

    const float4* xr = reinterpret_cast<const float4*>(x + (size_t)b * FEAT_DIM);
    const int lab = labels[b];
    const float4* cr = reinterpret_cast<const float4*>(centers + (size_t)lab * FEAT_DIM);

    float acc = 0.0f;
    // FEAT_DIM/4 = 512 float4 elements; 256 threads -> 2 per thread
#pragma unroll
    for (int i = 0; i < FEAT_DIM / 4 / 256; ++i) {
        const int idx = t + i * 256;
        const float4 xv = xr[idx];
        const float4 cv = cr[idx];
        const float dx = xv.x - cv.x;
        const float dy = xv.y - cv.y;
        const float dz = xv.z - cv.z;
        const float dw = xv.w - cv.w;
        acc += dx * dx + dy * dy + dz * dz + dw * dw;
    }

    // wave-64 shuffle reduction
#pragma unroll
    for (int off = 32; off > 0; off >>= 1)
        acc += __shfl_down(acc, off, 64);

    __shared__ float wave_sums[4];
    const int wid = t >> 6;
    const int lane = t & 63;
    if (lane == 0) wave_sums[wid] = acc;
    __syncthreads();
    if (t == 0) {
        const float s = wave_sums[0] + wave_sums[1] + wave_sums[2] + wave_sums[3];
        row_dist[b] = s * (1.0f / (float)FEAT_DIM);
    }
}

// Kernel 2: single block reduces BATCH row distances -> clamp -> mean
__global__ void __launch_bounds__(256) center_reduce_kernel(
    const float* __restrict__ row_dist,
    float* __restrict__ out) {
    const int t = threadIdx.x;
    float acc = 0.0f;
#pragma unroll
    for (int i = 0; i < BATCH / 256; ++i) {
        float d = row_dist[t + i * 256];
        d = fminf(fmaxf(d, CLAMP_MIN), CLAMP_MAX);
        acc += d;
    }
#pragma unroll
    for (int off = 32; off > 0; off >>= 1)
        acc += __shfl_down(acc, off, 64);

    __shared__ float wave_sums[4];
    const int wid = t >> 6;
    const int lane = t & 63;
    if (lane == 0) wave_sums[wid] = acc;
    __syncthreads();
    if (t == 0) {
        out[0] = (wave_sums[0] + wave_sums[1] + wave_sums[2] + wave_sums[3]) *
                 (1.0f / (float)BATCH);
    }
}

extern "C" void kernel_launch(void* const* d_in, const int* in_sizes, int n_in,
                              void* d_out, int out_size, void* d_ws, size_t ws_size,
                              hipStream_t stream) {
    const float* x = (const float*)d_in[0];
    const int* labels = (const int*)d_in[1];
    const float* centers = (const float*)d_in[2];
    float* out = (float*)d_out;
    float* row_dist = (float*)d_ws;  // BATCH floats

    center_dist_kernel<<<BATCH, 256, 0, stream>>>(x, labels, centers, row_dist);
    center_reduce_kernel<<<1, 256, 0, stream>>>(row_dist, out);
}